// Round 1
// baseline (382.021 us; speedup 1.0000x reference)
//
#include <hip/hip_runtime.h>
#include <math.h>
#include <stdint.h>

#define TT 2048
#define BB 2
#define DD 768
#define HH 12
#define DHH 64
#define DTT 32
#define NROW 4096  // B*T

typedef float v4 __attribute__((ext_vector_type(4)));

__device__ __forceinline__ float wave_sum(float v) {
#pragma unroll
  for (int m = 32; m > 0; m >>= 1) v += __shfl_xor(v, m, 64);
  return v;
}
__device__ __forceinline__ float wave_max(float v) {
#pragma unroll
  for (int m = 32; m > 0; m >>= 1) v = fmaxf(v, __shfl_xor(v, m, 64));
  return v;
}

// ---------------- Kernel A: time tables (+ zero M accumulator) ----------------
__global__ __launch_bounds__(256) void time_tables(
    const float* __restrict__ tang, const float* __restrict__ hdelta,
    float* __restrict__ timeq, float* __restrict__ timek, float* __restrict__ M) {
  int idx = blockIdx.x * 256 + threadIdx.x;
  if (idx < BB * HH * DHH * DHH) M[idx] = 0.f;  // 98304 M accumulators
  if (idx >= TT * HH * DTT) return;
  int d = idx % DTT;
  int h = (idx / DTT) % HH;
  int t = idx / (DTT * HH);
  float ang = tang[h * DTT + d];
  float sk, ck, sq, cq;
  sincosf((float)t * ang, &sk, &ck);
  sincosf(((float)t + hdelta[h]) * ang, &sq, &cq);
  timek[t * DD + h * DHH + d]       = (ck + sk) * 0.125f;
  timek[t * DD + h * DHH + d + DTT] = (ck - sk) * 0.125f;
  timeq[t * DD + h * DHH + d]       = (cq + sq) * 0.125f;
  timeq[t * DD + h * DHH + d + DTT] = (cq - sq) * 0.125f;
}

// ---------------- Kernel B1: fused QKV GEMM  C[4096 x 2304] = A[4096x768] * W^T ----
__global__ __launch_bounds__(256) void gemm_qkv(
    const float* __restrict__ A, const float* __restrict__ Wq,
    const float* __restrict__ Wk, const float* __restrict__ Wv,
    float* __restrict__ C) {
  __shared__ float As[64][68];
  __shared__ float Ws[64][68];  // transposed: Ws[k][j]
  int i0 = blockIdx.y * 64;
  int j0 = blockIdx.x * 64;
  const float* Wsel;
  int jb;
  if (j0 < 768) { Wsel = Wq; jb = j0; }
  else if (j0 < 1536) { Wsel = Wk; jb = j0 - 768; }
  else { Wsel = Wv; jb = j0 - 1536; }
  int tid = threadIdx.x;
  int tx = tid & 15, ty = tid >> 4;
  float acc[4][4] = {};
  for (int kb = 0; kb < 768; kb += 64) {
#pragma unroll
    for (int p = 0; p < 4; ++p) {
      int f = tid + 256 * p;
      int r = f >> 4, c4 = (f & 15) << 2;
      v4 av = *(const v4*)&A[(size_t)(i0 + r) * 768 + kb + c4];
      *(v4*)&As[r][c4] = av;
      v4 wv = *(const v4*)&Wsel[(size_t)(jb + r) * 768 + kb + c4];
      Ws[c4 + 0][r] = wv[0];
      Ws[c4 + 1][r] = wv[1];
      Ws[c4 + 2][r] = wv[2];
      Ws[c4 + 3][r] = wv[3];
    }
    __syncthreads();
#pragma unroll
    for (int k4 = 0; k4 < 64; k4 += 4) {
      v4 a[4], b[4];
#pragma unroll
      for (int r = 0; r < 4; ++r) a[r] = *(const v4*)&As[ty * 4 + r][k4];
#pragma unroll
      for (int m = 0; m < 4; ++m) b[m] = *(const v4*)&Ws[k4 + m][tx * 4];
#pragma unroll
      for (int m = 0; m < 4; ++m)
#pragma unroll
        for (int r = 0; r < 4; ++r)
#pragma unroll
          for (int c = 0; c < 4; ++c) acc[r][c] += a[r][m] * b[m][c];
    }
    __syncthreads();
  }
#pragma unroll
  for (int r = 0; r < 4; ++r)
#pragma unroll
    for (int c = 0; c < 4; ++c)
      C[(size_t)(i0 + ty * 4 + r) * 2304 + j0 + tx * 4 + c] = acc[r][c];
}

// ---------------- Kernel B2: per-(b,t,h) fuse: qsum, softmax(k)*v ----------------
__global__ __launch_bounds__(256) void fuse_qkv(
    const float* __restrict__ qkv, const float* __restrict__ bk,
    const float* __restrict__ bv, const float* __restrict__ qb,
    const int* __restrict__ amask, float* __restrict__ kvout,
    float* __restrict__ qsum) {
  int w = (blockIdx.x << 2) + (threadIdx.x >> 6);  // global wave id
  int lane = threadIdx.x & 63;
  if (w >= NROW * HH) return;
  int h = w % HH;
  int i = w / HH;  // i = b*T + t
  float mk = (float)amask[i];
  const float* row = qkv + (size_t)i * 2304;
  int col = h * DHH + lane;
  // q path
  float qraw = row[col] - expf(qb[col]);
  float q = (1.f / (1.f + expf(-qraw))) * (1.0f / 64.0f) * mk;
  float qs = wave_sum(q);
  if (lane == 0) qsum[i * HH + h] = qs;
  // k softmax
  float kval = (row[768 + col] + bk[col]) * mk;  // KTEMP = 1
  float kmax = wave_max(kval);
  float e = expf(kval - kmax);
  float es = wave_sum(e);
  float p = e / es;
  // v
  float vval = row[1536 + col] + bv[col];
  kvout[((size_t)i * HH + h) * DHH + lane] = p * vval;
}

// ---------------- Kernel C: M[b,h] = sum_t timek[t,h,:]^T kv[b,t,h,:] ----------------
__global__ __launch_bounds__(256) void calc_M(
    const float* __restrict__ timek, const float* __restrict__ kv,
    float* __restrict__ M) {
  int blk = blockIdx.x;  // B*H*8 = 192
  int split = blk & 7;
  int bh = blk >> 3;
  int b = bh / HH, h = bh % HH;
  __shared__ float Tk[64][68];
  __shared__ float Kv[64][68];
  int tid = threadIdx.x;
  int tx = tid & 15, ty = tid >> 4;
  float acc[4][4] = {};
  int t0 = split * 256;
  for (int tt = 0; tt < 256; tt += 64) {
#pragma unroll
    for (int p = 0; p < 4; ++p) {
      int f = tid + 256 * p;
      int r = f >> 4, c4 = (f & 15) << 2;
      int t = t0 + tt + r;
      *(v4*)&Tk[r][c4] = *(const v4*)&timek[(size_t)t * DD + h * DHH + c4];
      *(v4*)&Kv[r][c4] =
          *(const v4*)&kv[((size_t)(b * TT + t) * HH + h) * DHH + c4];
    }
    __syncthreads();
#pragma unroll
    for (int kk = 0; kk < 64; ++kk) {
      v4 a = *(const v4*)&Tk[kk][ty * 4];
      v4 bv4 = *(const v4*)&Kv[kk][tx * 4];
#pragma unroll
      for (int r = 0; r < 4; ++r)
#pragma unroll
        for (int c = 0; c < 4; ++c) acc[r][c] += a[r] * bv4[c];
    }
    __syncthreads();
  }
#pragma unroll
  for (int r = 0; r < 4; ++r)
#pragma unroll
    for (int c = 0; c < 4; ++c)
      atomicAdd(&M[(size_t)bh * 4096 + (ty * 4 + r) * 64 + tx * 4 + c],
                acc[r][c]);
}

// ---------------- Kernel D1: loading[b,t,h,:] = qsum * (timeq[t,h,:] @ M[b,h]) -------
__global__ __launch_bounds__(256) void calc_loading(
    const float* __restrict__ timeq, const float* __restrict__ M,
    const float* __restrict__ qsum, float* __restrict__ loading) {
  int blk = blockIdx.x;  // B*H*16 = 384, each handles 128 t's
  int tc = blk & 15;
  int bh = blk >> 4;
  int b = bh / HH, h = bh % HH;
  __shared__ float Ml[4096];
  for (int p = threadIdx.x; p < 4096; p += 256) Ml[p] = M[(size_t)bh * 4096 + p];
  __syncthreads();
  int w = threadIdx.x >> 6, lane = threadIdx.x & 63;
  for (int it = 0; it < 32; ++it) {
    int t = tc * 128 + w * 32 + it;
    int i = b * TT + t;
    float tq = timeq[(size_t)t * DD + h * DHH + lane];
    float acc = 0.f;
#pragma unroll
    for (int r = 0; r < 64; ++r)
      acc = fmaf(__shfl(tq, r, 64), Ml[r * 64 + lane], acc);
    loading[(size_t)i * DD + h * DHH + lane] = qsum[i * HH + h] * acc;
  }
}

// ---------------- Kernel D2: X = loading @ Wo^T + bo + states ----------------
__global__ __launch_bounds__(256) void gemm_out(
    const float* __restrict__ A, const float* __restrict__ Wo,
    const float* __restrict__ bo, const float* __restrict__ states,
    float* __restrict__ X) {
  __shared__ float As[64][68];
  __shared__ float Ws[64][68];
  int i0 = blockIdx.y * 64;
  int j0 = blockIdx.x * 64;
  int tid = threadIdx.x;
  int tx = tid & 15, ty = tid >> 4;
  float acc[4][4] = {};
  for (int kb = 0; kb < 768; kb += 64) {
#pragma unroll
    for (int p = 0; p < 4; ++p) {
      int f = tid + 256 * p;
      int r = f >> 4, c4 = (f & 15) << 2;
      v4 av = *(const v4*)&A[(size_t)(i0 + r) * 768 + kb + c4];
      *(v4*)&As[r][c4] = av;
      v4 wv = *(const v4*)&Wo[(size_t)(j0 + r) * 768 + kb + c4];
      Ws[c4 + 0][r] = wv[0];
      Ws[c4 + 1][r] = wv[1];
      Ws[c4 + 2][r] = wv[2];
      Ws[c4 + 3][r] = wv[3];
    }
    __syncthreads();
#pragma unroll
    for (int k4 = 0; k4 < 64; k4 += 4) {
      v4 a[4], b[4];
#pragma unroll
      for (int r = 0; r < 4; ++r) a[r] = *(const v4*)&As[ty * 4 + r][k4];
#pragma unroll
      for (int m = 0; m < 4; ++m) b[m] = *(const v4*)&Ws[k4 + m][tx * 4];
#pragma unroll
      for (int m = 0; m < 4; ++m)
#pragma unroll
        for (int r = 0; r < 4; ++r)
#pragma unroll
          for (int c = 0; c < 4; ++c) acc[r][c] += a[r][m] * b[m][c];
    }
    __syncthreads();
  }
#pragma unroll
  for (int r = 0; r < 4; ++r) {
    int i = i0 + ty * 4 + r;
#pragma unroll
    for (int c = 0; c < 4; ++c) {
      int j = j0 + tx * 4 + c;
      X[(size_t)i * 768 + j] = acc[r][c] + bo[j] + states[(size_t)i * 768 + j];
    }
  }
}

// ---------------- Kernel E: LayerNorm ----------------
__global__ __launch_bounds__(256) void layernorm(
    const float* __restrict__ X, const float* __restrict__ gamma,
    const float* __restrict__ beta, float* __restrict__ out) {
  int i = blockIdx.x;
  const float* x = X + (size_t)i * 768;
  float vals[3];
  float s = 0.f, s2 = 0.f;
#pragma unroll
  for (int p = 0; p < 3; ++p) {
    float v = x[threadIdx.x + 256 * p];
    vals[p] = v;
    s += v;
    s2 += v * v;
  }
  s = wave_sum(s);
  s2 = wave_sum(s2);
  __shared__ float red[8];
  int w = threadIdx.x >> 6;
  if ((threadIdx.x & 63) == 0) {
    red[w] = s;
    red[4 + w] = s2;
  }
  __syncthreads();
  float stot = red[0] + red[1] + red[2] + red[3];
  float s2tot = red[4] + red[5] + red[6] + red[7];
  float mu = stot * (1.f / 768.f);
  float var = s2tot * (1.f / 768.f) - mu * mu;
  float rs = rsqrtf(var + 1e-5f);
#pragma unroll
  for (int p = 0; p < 3; ++p) {
    int j = threadIdx.x + 256 * p;
    out[(size_t)i * 768 + j] = (vals[p] - mu) * rs * gamma[j] + beta[j];
  }
}

extern "C" void kernel_launch(void* const* d_in, const int* in_sizes, int n_in,
                              void* d_out, int out_size, void* d_ws,
                              size_t ws_size, hipStream_t stream) {
  const float* states = (const float*)d_in[0];
  const int* amask    = (const int*)d_in[1];
  const float* Wq     = (const float*)d_in[2];
  const float* Wk     = (const float*)d_in[3];
  const float* bk     = (const float*)d_in[4];
  const float* Wv     = (const float*)d_in[5];
  const float* bv     = (const float*)d_in[6];
  const float* Wo     = (const float*)d_in[7];
  const float* bo     = (const float*)d_in[8];
  const float* qb     = (const float*)d_in[9];
  const float* tang   = (const float*)d_in[10];
  const float* hdelta = (const float*)d_in[11];
  const float* gamma  = (const float*)d_in[12];
  const float* beta   = (const float*)d_in[13];
  float* out = (float*)d_out;
  float* ws = (float*)d_ws;

  // workspace layout (floats)
  float* timeq   = ws + 0;
  float* timek   = ws + 1572864;
  float* qkv     = ws + 3145728;   // 4096 x 2304
  float* kvbuf   = ws + 12582912;  // B*T*H*64
  float* qsum    = ws + 15728640;  // B*T*H
  float* Mbuf    = ws + 15777792;  // B*H*64*64
  float* loading = qkv;            // reuse Q region (dead after fuse_qkv)
  float* xbuf    = qkv + 3145728;  // reuse K region

  time_tables<<<3072, 256, 0, stream>>>(tang, hdelta, timeq, timek, Mbuf);
  gemm_qkv<<<dim3(36, 64), 256, 0, stream>>>(states, Wq, Wk, Wv, qkv);
  fuse_qkv<<<12288, 256, 0, stream>>>(qkv, bk, bv, qb, amask, kvbuf, qsum);
  calc_M<<<192, 256, 0, stream>>>(timek, kvbuf, Mbuf);
  calc_loading<<<384, 256, 0, stream>>>(timeq, Mbuf, qsum, loading);
  gemm_out<<<dim3(12, 64), 256, 0, stream>>>(loading, Wo, bo, states, xbuf);
  layernorm<<<4096, 256, 0, stream>>>(xbuf, gamma, beta, out);
}

// Round 2
// 158.259 us; speedup vs baseline: 2.4139x; 2.4139x over previous
//
#include <hip/hip_runtime.h>
#include <math.h>
#include <stdint.h>

#define TT 2048
#define BB 2
#define DD 768
#define HH 12
#define DHH 64
#define DTT 32
#define NROW 4096  // B*T

typedef float v4 __attribute__((ext_vector_type(4)));
typedef __attribute__((ext_vector_type(8))) short s8v;      // 8 bf16 (4 VGPRs)
typedef __attribute__((ext_vector_type(4))) float f4v;      // MFMA acc
typedef unsigned short u16;
typedef __attribute__((ext_vector_type(4))) unsigned short us4;

__device__ __forceinline__ float wave_sum(float v) {
#pragma unroll
  for (int m = 32; m > 0; m >>= 1) v += __shfl_xor(v, m, 64);
  return v;
}
__device__ __forceinline__ float wave_max(float v) {
#pragma unroll
  for (int m = 32; m > 0; m >>= 1) v = fmaxf(v, __shfl_xor(v, m, 64));
  return v;
}
__device__ __forceinline__ u16 f2bf(float x) {
  unsigned u = __builtin_bit_cast(unsigned, x);
  u += 0x7fffu + ((u >> 16) & 1u);
  return (u16)(u >> 16);
}
__device__ __forceinline__ void gload16(const void* g, void* l) {
  __builtin_amdgcn_global_load_lds(
      (const __attribute__((address_space(1))) unsigned int*)g,
      (__attribute__((address_space(3))) unsigned int*)l, 16, 0, 0);
}

// ---------------- Kernel A: time tables (+ zero M accumulator) ----------------
__global__ __launch_bounds__(256) void time_tables(
    const float* __restrict__ tang, const float* __restrict__ hdelta,
    float* __restrict__ timeq, float* __restrict__ timek, float* __restrict__ M) {
  int idx = blockIdx.x * 256 + threadIdx.x;
  if (idx < BB * HH * DHH * DHH) M[idx] = 0.f;
  if (idx >= TT * HH * DTT) return;
  int d = idx % DTT;
  int h = (idx / DTT) % HH;
  int t = idx / (DTT * HH);
  float ang = tang[h * DTT + d];
  float sk, ck, sq, cq;
  sincosf((float)t * ang, &sk, &ck);
  sincosf(((float)t + hdelta[h]) * ang, &sq, &cq);
  timek[t * DD + h * DHH + d]       = (ck + sk) * 0.125f;
  timek[t * DD + h * DHH + d + DTT] = (ck - sk) * 0.125f;
  timeq[t * DD + h * DHH + d]       = (cq + sq) * 0.125f;
  timeq[t * DD + h * DHH + d + DTT] = (cq - sq) * 0.125f;
}

// ---------------- Convert: f32 -> bf16 (states, Wq|Wk|Wv concat, Wo) ----------
__global__ __launch_bounds__(256) void convert_bf16(
    const float* __restrict__ s, const float* __restrict__ wq,
    const float* __restrict__ wk, const float* __restrict__ wv,
    const float* __restrict__ wo, u16* __restrict__ sb,
    u16* __restrict__ wqkvb, u16* __restrict__ wob) {
  int idx = (blockIdx.x * 256 + threadIdx.x) * 4;
  const float* src;
  u16* dst;
  int off;
  if (idx < 3145728) { src = s; dst = sb; off = idx; }
  else if (idx < 3735552) { src = wq; dst = wqkvb; off = idx - 3145728; }
  else if (idx < 4325376) { src = wk; dst = wqkvb + 589824; off = idx - 3735552; }
  else if (idx < 4915200) { src = wv; dst = wqkvb + 1179648; off = idx - 4325376; }
  else { src = wo; dst = wob; off = idx - 4915200; }
  v4 f = *(const v4*)&src[off];
  us4 o;
#pragma unroll
  for (int j = 0; j < 4; ++j) o[j] = f2bf(f[j]);
  *(us4*)&dst[off] = o;
}

// ---------------- MFMA GEMM: C[M][N] = A[M][K](bf16) * B[N][K]^T(bf16) --------
// 128x128 tile, BK=32, 4 waves (2x2), each wave 64x64 via 4x4 frags of 16x16x32.
template <int EPI>
__global__ __launch_bounds__(256) void gemm_bt(
    const u16* __restrict__ A, const u16* __restrict__ B, float* __restrict__ C,
    const float* __restrict__ bias, const float* __restrict__ res,
    int M, int N, int K) {
  __shared__ __align__(16) u16 As[2][4096];
  __shared__ __align__(16) u16 Bs[2][4096];
  const int tid = threadIdx.x;
  const int l = tid & 63;
  const int w = tid >> 6;
  const int wr = w >> 1, wc = w & 1;
  const int i0 = blockIdx.y * 128, j0 = blockIdx.x * 128;
  const int srow = tid >> 2, scol = (tid & 3) * 8;
  const u16* gA0 = A + (size_t)(i0 + srow) * K + scol;
  const u16* gA1 = gA0 + (size_t)64 * K;
  const u16* gB0 = B + (size_t)(j0 + srow) * K + scol;
  const u16* gB1 = gB0 + (size_t)64 * K;
  const int lo = tid * 8;

  f4v acc[4][4];
#pragma unroll
  for (int m = 0; m < 4; ++m)
#pragma unroll
    for (int n = 0; n < 4; ++n) acc[m][n] = (f4v){0.f, 0.f, 0.f, 0.f};

  // prologue stage into buf 0
  gload16(gA0, &As[0][lo]);
  gload16(gA1, &As[0][2048 + lo]);
  gload16(gB0, &Bs[0][lo]);
  gload16(gB1, &Bs[0][2048 + lo]);

  const int KT = K >> 5;
  const int ar = wr * 64 + (l & 15);
  const int br = wc * 64 + (l & 15);
  const int kx = (l >> 4) * 8;
  int cur = 0;
  for (int kt = 0; kt < KT; ++kt) {
    __syncthreads();  // staged buf[cur] complete (vmcnt drained at barrier)
    if (kt + 1 < KT) {
      int kb = (kt + 1) << 5;
      int nb = cur ^ 1;
      gload16(gA0 + kb, &As[nb][lo]);
      gload16(gA1 + kb, &As[nb][2048 + lo]);
      gload16(gB0 + kb, &Bs[nb][lo]);
      gload16(gB1 + kb, &Bs[nb][2048 + lo]);
    }
    s8v af[4], bf[4];
#pragma unroll
    for (int m = 0; m < 4; ++m)
      af[m] = *(const s8v*)&As[cur][(ar + m * 16) * 32 + kx];
#pragma unroll
    for (int n = 0; n < 4; ++n)
      bf[n] = *(const s8v*)&Bs[cur][(br + n * 16) * 32 + kx];
#pragma unroll
    for (int m = 0; m < 4; ++m)
#pragma unroll
      for (int n = 0; n < 4; ++n)
        acc[m][n] =
            __builtin_amdgcn_mfma_f32_16x16x32_bf16(af[m], bf[n], acc[m][n], 0, 0, 0);
    __syncthreads();  // all waves done reading buf[cur] before restage
    cur ^= 1;
  }

  // epilogue: C/D frag layout col=lane&15, row=(lane>>4)*4+r  [m89]
  const int crow = i0 + wr * 64 + (l >> 4) * 4;
  const int ccol = j0 + wc * 64 + (l & 15);
#pragma unroll
  for (int m = 0; m < 4; ++m)
#pragma unroll
    for (int n = 0; n < 4; ++n) {
      int col = ccol + n * 16;
      size_t base = (size_t)(crow + m * 16) * N + col;
#pragma unroll
      for (int r = 0; r < 4; ++r) {
        float vv = acc[m][n][r];
        if (EPI) vv += bias[col] + res[base + (size_t)r * N];
        C[base + (size_t)r * N] = vv;
      }
    }
}

// ---------------- per-(b,t,h) fuse: qsum, softmax(k)*v ----------------
__global__ __launch_bounds__(256) void fuse_qkv(
    const float* __restrict__ qkv, const float* __restrict__ bk,
    const float* __restrict__ bv, const float* __restrict__ qb,
    const int* __restrict__ amask, float* __restrict__ kvout,
    float* __restrict__ qsum) {
  int w = (blockIdx.x << 2) + (threadIdx.x >> 6);
  int lane = threadIdx.x & 63;
  if (w >= NROW * HH) return;
  int h = w % HH;
  int i = w / HH;
  float mk = (float)amask[i];
  const float* row = qkv + (size_t)i * 2304;
  int col = h * DHH + lane;
  float qraw = row[col] - expf(qb[col]);
  float q = (1.f / (1.f + expf(-qraw))) * (1.0f / 64.0f) * mk;
  float qs = wave_sum(q);
  if (lane == 0) qsum[i * HH + h] = qs;
  float kval = (row[768 + col] + bk[col]) * mk;
  float kmax = wave_max(kval);
  float e = expf(kval - kmax);
  float es = wave_sum(e);
  float p = e / es;
  float vval = row[1536 + col] + bv[col];
  kvout[((size_t)i * HH + h) * DHH + lane] = p * vval;
}

// ---------------- M[b,h] = sum_t timek[t,h,:]^T kv[b,t,h,:] ----------------
__global__ __launch_bounds__(256) void calc_M(
    const float* __restrict__ timek, const float* __restrict__ kv,
    float* __restrict__ M) {
  int blk = blockIdx.x;
  int split = blk & 7;
  int bh = blk >> 3;
  int b = bh / HH, h = bh % HH;
  __shared__ float Tk[64][68];
  __shared__ float Kv[64][68];
  int tid = threadIdx.x;
  int tx = tid & 15, ty = tid >> 4;
  float acc[4][4] = {};
  int t0 = split * 256;
  for (int tt = 0; tt < 256; tt += 64) {
#pragma unroll
    for (int p = 0; p < 4; ++p) {
      int f = tid + 256 * p;
      int r = f >> 4, c4 = (f & 15) << 2;
      int t = t0 + tt + r;
      *(v4*)&Tk[r][c4] = *(const v4*)&timek[(size_t)t * DD + h * DHH + c4];
      *(v4*)&Kv[r][c4] =
          *(const v4*)&kv[((size_t)(b * TT + t) * HH + h) * DHH + c4];
    }
    __syncthreads();
#pragma unroll
    for (int kk = 0; kk < 64; ++kk) {
      v4 a = *(const v4*)&Tk[kk][ty * 4];
      v4 bv4 = *(const v4*)&Kv[kk][tx * 4];
#pragma unroll
      for (int r = 0; r < 4; ++r)
#pragma unroll
        for (int c = 0; c < 4; ++c) acc[r][c] += a[r] * bv4[c];
    }
    __syncthreads();
  }
#pragma unroll
  for (int r = 0; r < 4; ++r)
#pragma unroll
    for (int c = 0; c < 4; ++c)
      atomicAdd(&M[(size_t)bh * 4096 + (ty * 4 + r) * 64 + tx * 4 + c],
                acc[r][c]);
}

// -------- loading[b,t,h,:] = qsum * (timeq[t,h,:] @ M[b,h])  -> bf16 ----------
__global__ __launch_bounds__(256) void calc_loading(
    const float* __restrict__ timeq, const float* __restrict__ M,
    const float* __restrict__ qsum, u16* __restrict__ loading) {
  int blk = blockIdx.x;
  int tc = blk & 15;
  int bh = blk >> 4;
  int b = bh / HH, h = bh % HH;
  __shared__ float Ml[4096];
  for (int p = threadIdx.x; p < 4096; p += 256) Ml[p] = M[(size_t)bh * 4096 + p];
  __syncthreads();
  int w = threadIdx.x >> 6, lane = threadIdx.x & 63;
  for (int it = 0; it < 32; ++it) {
    int t = tc * 128 + w * 32 + it;
    int i = b * TT + t;
    float tq = timeq[(size_t)t * DD + h * DHH + lane];
    float acc = 0.f;
#pragma unroll
    for (int r = 0; r < 64; ++r)
      acc = fmaf(__shfl(tq, r, 64), Ml[r * 64 + lane], acc);
    loading[(size_t)i * DD + h * DHH + lane] = f2bf(qsum[i * HH + h] * acc);
  }
}

// ---------------- LayerNorm ----------------
__global__ __launch_bounds__(256) void layernorm(
    const float* __restrict__ X, const float* __restrict__ gamma,
    const float* __restrict__ beta, float* __restrict__ out) {
  int i = blockIdx.x;
  const float* x = X + (size_t)i * 768;
  float vals[3];
  float s = 0.f, s2 = 0.f;
#pragma unroll
  for (int p = 0; p < 3; ++p) {
    float v = x[threadIdx.x + 256 * p];
    vals[p] = v;
    s += v;
    s2 += v * v;
  }
  s = wave_sum(s);
  s2 = wave_sum(s2);
  __shared__ float red[8];
  int w = threadIdx.x >> 6;
  if ((threadIdx.x & 63) == 0) {
    red[w] = s;
    red[4 + w] = s2;
  }
  __syncthreads();
  float stot = red[0] + red[1] + red[2] + red[3];
  float s2tot = red[4] + red[5] + red[6] + red[7];
  float mu = stot * (1.f / 768.f);
  float var = s2tot * (1.f / 768.f) - mu * mu;
  float rs = rsqrtf(var + 1e-5f);
#pragma unroll
  for (int p = 0; p < 3; ++p) {
    int j = threadIdx.x + 256 * p;
    out[(size_t)i * 768 + j] = (vals[p] - mu) * rs * gamma[j] + beta[j];
  }
}

extern "C" void kernel_launch(void* const* d_in, const int* in_sizes, int n_in,
                              void* d_out, int out_size, void* d_ws,
                              size_t ws_size, hipStream_t stream) {
  const float* states = (const float*)d_in[0];
  const int* amask    = (const int*)d_in[1];
  const float* Wq     = (const float*)d_in[2];
  const float* Wk     = (const float*)d_in[3];
  const float* bk     = (const float*)d_in[4];
  const float* Wv     = (const float*)d_in[5];
  const float* bv     = (const float*)d_in[6];
  const float* Wo     = (const float*)d_in[7];
  const float* bo     = (const float*)d_in[8];
  const float* qb     = (const float*)d_in[9];
  const float* tang   = (const float*)d_in[10];
  const float* hdelta = (const float*)d_in[11];
  const float* gamma  = (const float*)d_in[12];
  const float* beta   = (const float*)d_in[13];
  float* out = (float*)d_out;
  float* ws = (float*)d_ws;

  // workspace layout (float units)
  float* timeq  = ws + 0;                      // 1,572,864
  float* timek  = ws + 1572864;                // 1,572,864
  float* qkv    = ws + 3145728;                // 9,437,184 (dead after fuse_qkv)
  float* kvbuf  = ws + 12582912;               // 3,145,728
  float* qsum   = ws + 15728640;               // 49,152
  float* Mbuf   = ws + 15777792;               // 98,304
  u16* Abf      = (u16*)(ws + 15876096);       // 3,145,728 u16
  u16* Wqkvb    = (u16*)(ws + 17448960);       // 1,769,472 u16
  u16* Wob      = (u16*)(ws + 18333696);       // 589,824 u16
  // reuse of dead qkv region:
  u16* loadb    = (u16*)(ws + 3145728);        // 3,145,728 u16
  float* xbuf   = ws + 4718592;                // 3,145,728 f32

  time_tables<<<3072, 256, 0, stream>>>(tang, hdelta, timeq, timek, Mbuf);
  convert_bf16<<<5376, 256, 0, stream>>>(states, Wq, Wk, Wv, Wo, Abf, Wqkvb, Wob);
  gemm_bt<0><<<dim3(18, 32), 256, 0, stream>>>(Abf, Wqkvb, qkv, nullptr, nullptr,
                                               4096, 2304, 768);
  fuse_qkv<<<12288, 256, 0, stream>>>(qkv, bk, bv, qb, amask, kvbuf, qsum);
  calc_M<<<192, 256, 0, stream>>>(timek, kvbuf, Mbuf);
  calc_loading<<<384, 256, 0, stream>>>(timeq, Mbuf, qsum, loadb);
  gemm_bt<1><<<dim3(6, 32), 256, 0, stream>>>(loadb, Wob, xbuf, bo, states,
                                              4096, 768, 768);
  layernorm<<<4096, 256, 0, stream>>>(xbuf, gamma, beta, out);
}

// Round 4
// 103.792 us; speedup vs baseline: 3.6806x; 1.5248x over previous
//
#include <hip/hip_runtime.h>
#include <math.h>
#include <stdint.h>

#define TT 2048
#define BB 2
#define DD 768
#define HH 12
#define DHH 64
#define DTT 32
#define NROW 4096  // B*T

typedef float v4 __attribute__((ext_vector_type(4)));
typedef __attribute__((ext_vector_type(8))) short s8v;      // 8 bf16 (4 VGPRs)
typedef __attribute__((ext_vector_type(4))) float f4v;      // MFMA acc
typedef unsigned short u16;
typedef __attribute__((ext_vector_type(4))) unsigned short us4;

__device__ __forceinline__ float wave_sum(float v) {
#pragma unroll
  for (int m = 32; m > 0; m >>= 1) v += __shfl_xor(v, m, 64);
  return v;
}
__device__ __forceinline__ float wave_max(float v) {
#pragma unroll
  for (int m = 32; m > 0; m >>= 1) v = fmaxf(v, __shfl_xor(v, m, 64));
  return v;
}
__device__ __forceinline__ u16 f2bf(float x) {
  unsigned u = __builtin_bit_cast(unsigned, x);
  u += 0x7fffu + ((u >> 16) & 1u);
  return (u16)(u >> 16);
}
__device__ __forceinline__ float bf2f(u16 b) {
  return __builtin_bit_cast(float, (unsigned)b << 16);
}
__device__ __forceinline__ void gload16(const void* g, void* l) {
  __builtin_amdgcn_global_load_lds(
      (const __attribute__((address_space(1))) unsigned int*)g,
      (__attribute__((address_space(3))) unsigned int*)l, 16, 0, 0);
}

// ------- Kernel A: time tables (timeq -> bf16, timek -> f32) -------
__global__ __launch_bounds__(256) void time_tables(
    const float* __restrict__ tang, const float* __restrict__ hdelta,
    u16* __restrict__ timeqb, float* __restrict__ timek) {
  int idx = blockIdx.x * 256 + threadIdx.x;
  if (idx >= TT * HH * DTT) return;
  int d = idx % DTT;
  int h = (idx / DTT) % HH;
  int t = idx / (DTT * HH);
  float ang = tang[h * DTT + d];
  float sk, ck, sq, cq;
  sincosf((float)t * ang, &sk, &ck);
  sincosf(((float)t + hdelta[h]) * ang, &sq, &cq);
  timek[t * DD + h * DHH + d]       = (ck + sk) * 0.125f;
  timek[t * DD + h * DHH + d + DTT] = (ck - sk) * 0.125f;
  timeqb[t * DD + h * DHH + d]       = f2bf((cq + sq) * 0.125f);
  timeqb[t * DD + h * DHH + d + DTT] = f2bf((cq - sq) * 0.125f);
}

// ---------------- Convert: f32 -> bf16 (states, Wq|Wk|Wv concat, Wo) ----------
__global__ __launch_bounds__(256) void convert_bf16(
    const float* __restrict__ s, const float* __restrict__ wq,
    const float* __restrict__ wk, const float* __restrict__ wv,
    const float* __restrict__ wo, u16* __restrict__ sb,
    u16* __restrict__ wqkvb, u16* __restrict__ wob) {
  int idx = (blockIdx.x * 256 + threadIdx.x) * 4;
  const float* src;
  u16* dst;
  int off;
  if (idx < 3145728) { src = s; dst = sb; off = idx; }
  else if (idx < 3735552) { src = wq; dst = wqkvb; off = idx - 3145728; }
  else if (idx < 4325376) { src = wk; dst = wqkvb + 589824; off = idx - 3735552; }
  else if (idx < 4915200) { src = wv; dst = wqkvb + 1179648; off = idx - 4325376; }
  else { src = wo; dst = wob; off = idx - 4915200; }
  v4 f = *(const v4*)&src[off];
  us4 o;
#pragma unroll
  for (int j = 0; j < 4; ++j) o[j] = f2bf(f[j]);
  *(us4*)&dst[off] = o;
}

// ---------------- MFMA GEMM: C[M][N] = A[M][K](bf16) * B[N][K]^T(bf16) --------
// 128x128 tile, BK=32, 4 waves. OBF: write bf16, else f32. EPI: +bias+res.
template <int EPI, int OBF>
__global__ __launch_bounds__(256) void gemm_bt(
    const u16* __restrict__ A, const u16* __restrict__ B, void* __restrict__ Cv,
    const float* __restrict__ bias, const float* __restrict__ res,
    int M, int N, int K) {
  __shared__ __align__(16) u16 As[2][4096];
  __shared__ __align__(16) u16 Bs[2][4096];
  const int tid = threadIdx.x;
  const int l = tid & 63;
  const int w = tid >> 6;
  const int wr = w >> 1, wc = w & 1;
  const int i0 = blockIdx.y * 128, j0 = blockIdx.x * 128;
  const int srow = tid >> 2, scol = (tid & 3) * 8;
  const u16* gA0 = A + (size_t)(i0 + srow) * K + scol;
  const u16* gA1 = gA0 + (size_t)64 * K;
  const u16* gB0 = B + (size_t)(j0 + srow) * K + scol;
  const u16* gB1 = gB0 + (size_t)64 * K;
  const int lo = tid * 8;

  f4v acc[4][4];
#pragma unroll
  for (int m = 0; m < 4; ++m)
#pragma unroll
    for (int n = 0; n < 4; ++n) acc[m][n] = (f4v){0.f, 0.f, 0.f, 0.f};

  gload16(gA0, &As[0][lo]);
  gload16(gA1, &As[0][2048 + lo]);
  gload16(gB0, &Bs[0][lo]);
  gload16(gB1, &Bs[0][2048 + lo]);

  const int KT = K >> 5;
  const int ar = wr * 64 + (l & 15);
  const int br = wc * 64 + (l & 15);
  const int kx = (l >> 4) * 8;
  int cur = 0;
  for (int kt = 0; kt < KT; ++kt) {
    __syncthreads();
    if (kt + 1 < KT) {
      int kb = (kt + 1) << 5;
      int nb = cur ^ 1;
      gload16(gA0 + kb, &As[nb][lo]);
      gload16(gA1 + kb, &As[nb][2048 + lo]);
      gload16(gB0 + kb, &Bs[nb][lo]);
      gload16(gB1 + kb, &Bs[nb][2048 + lo]);
    }
    s8v af[4], bf[4];
#pragma unroll
    for (int m = 0; m < 4; ++m)
      af[m] = *(const s8v*)&As[cur][(ar + m * 16) * 32 + kx];
#pragma unroll
    for (int n = 0; n < 4; ++n)
      bf[n] = *(const s8v*)&Bs[cur][(br + n * 16) * 32 + kx];
#pragma unroll
    for (int m = 0; m < 4; ++m)
#pragma unroll
      for (int n = 0; n < 4; ++n)
        acc[m][n] =
            __builtin_amdgcn_mfma_f32_16x16x32_bf16(af[m], bf[n], acc[m][n], 0, 0, 0);
    __syncthreads();
    cur ^= 1;
  }

  // C/D frag layout: col=lane&15, row=(lane>>4)*4+r
  const int crow = i0 + wr * 64 + (l >> 4) * 4;
  const int ccol = j0 + wc * 64 + (l & 15);
#pragma unroll
  for (int m = 0; m < 4; ++m)
#pragma unroll
    for (int n = 0; n < 4; ++n) {
      int col = ccol + n * 16;
      size_t base = (size_t)(crow + m * 16) * N + col;
#pragma unroll
      for (int r = 0; r < 4; ++r) {
        float vv = acc[m][n][r];
        if (EPI) vv += bias[col] + res[base + (size_t)r * N];
        if (OBF)
          ((u16*)Cv)[base + (size_t)r * N] = f2bf(vv);
        else
          ((float*)Cv)[base + (size_t)r * N] = vv;
      }
    }
}

// ---------------- per-(b,t,h) fuse: qsum, softmax(k)*v (bf16 qkv in) ----------
__global__ __launch_bounds__(256) void fuse_qkv(
    const u16* __restrict__ qkvb, const float* __restrict__ bk,
    const float* __restrict__ bv, const float* __restrict__ qb,
    const int* __restrict__ amask, float* __restrict__ kvout,
    float* __restrict__ qsum) {
  int w = (blockIdx.x << 2) + (threadIdx.x >> 6);
  int lane = threadIdx.x & 63;
  if (w >= NROW * HH) return;
  int h = w % HH;
  int i = w / HH;
  float mk = (float)amask[i];
  const u16* row = qkvb + (size_t)i * 2304;
  int col = h * DHH + lane;
  float qraw = bf2f(row[col]) - expf(qb[col]);
  float q = (1.f / (1.f + expf(-qraw))) * (1.0f / 64.0f) * mk;
  float qs = wave_sum(q);
  if (lane == 0) qsum[i * HH + h] = qs;
  float kval = (bf2f(row[768 + col]) + bk[col]) * mk;
  float kmax = wave_max(kval);
  float e = expf(kval - kmax);
  float es = wave_sum(e);
  float p = e / es;
  float vval = bf2f(row[1536 + col]) + bv[col];
  kvout[((size_t)i * HH + h) * DHH + lane] = p * vval;
}

// --- Mpart[bh*16+split][d][r] = sum_t kv[b,t,h,d]*timek[t,h,r] (plain store) ---
__global__ __launch_bounds__(256) void calc_M(
    const float* __restrict__ timek, const float* __restrict__ kv,
    float* __restrict__ Mpart) {
  int blk = blockIdx.x;  // bh*16 + split, 384 blocks
  int split = blk & 15;
  int bh = blk >> 4;
  int b = bh / HH, h = bh % HH;
  __shared__ float Tk[64][68];
  __shared__ float Kv[64][68];
  int tid = threadIdx.x;
  int tx = tid & 15, ty = tid >> 4;
  float acc[4][4] = {};
  int t0 = split * 128;
  for (int tt = 0; tt < 128; tt += 64) {
#pragma unroll
    for (int p = 0; p < 4; ++p) {
      int f = tid + 256 * p;
      int r = f >> 4, c4 = (f & 15) << 2;
      int t = t0 + tt + r;
      *(v4*)&Tk[r][c4] = *(const v4*)&timek[(size_t)t * DD + h * DHH + c4];
      *(v4*)&Kv[r][c4] =
          *(const v4*)&kv[((size_t)(b * TT + t) * HH + h) * DHH + c4];
    }
    __syncthreads();
#pragma unroll
    for (int kk = 0; kk < 64; ++kk) {
      v4 a = *(const v4*)&Tk[kk][ty * 4];
      v4 bv4 = *(const v4*)&Kv[kk][tx * 4];
#pragma unroll
      for (int r = 0; r < 4; ++r)
#pragma unroll
        for (int c = 0; c < 4; ++c) acc[r][c] += a[r] * bv4[c];
    }
    __syncthreads();
  }
  // transposed within slice: Mt[d = tx*4+c][r = ty*4+r]
#pragma unroll
  for (int r = 0; r < 4; ++r)
#pragma unroll
    for (int c = 0; c < 4; ++c)
      Mpart[(size_t)blk * 4096 + (tx * 4 + c) * 64 + (ty * 4 + r)] = acc[r][c];
}

// ------- Mt[bh][p] = sum_{s<16} Mpart[bh*16+s][p]  (deterministic order) ------
__global__ __launch_bounds__(256) void reduce_M(
    const float* __restrict__ Mpart, float* __restrict__ Mt) {
  int idx = blockIdx.x * 256 + threadIdx.x;  // 384*256 = 98304
  int bh = idx >> 12;
  int p = idx & 4095;
  float s = 0.f;
#pragma unroll
  for (int sp = 0; sp < 16; ++sp)
    s += Mpart[(size_t)((bh << 4) + sp) * 4096 + p];
  Mt[(size_t)bh * 4096 + p] = s;
}

// ------ loading[b,t,h,:] = qsum * (timeq[t,h,:] @ M[b,h]) via MFMA -> bf16 ----
__global__ __launch_bounds__(256) void calc_loading_mfma(
    const u16* __restrict__ timeqb, const float* __restrict__ Mt,
    const float* __restrict__ qsum, u16* __restrict__ loading) {
  const int bh = blockIdx.y;
  const int b = bh / HH, h = bh % HH;
  const int t0 = blockIdx.x * 128;
  __shared__ __align__(16) u16 Ms[64 * 72];
  for (int p = threadIdx.x; p < 4096; p += 256)
    Ms[(p >> 6) * 72 + (p & 63)] = f2bf(Mt[(size_t)bh * 4096 + p]);
  __syncthreads();
  const int l = threadIdx.x & 63, w = threadIdx.x >> 6;
  f4v acc[2][4];
#pragma unroll
  for (int m = 0; m < 2; ++m)
#pragma unroll
    for (int n = 0; n < 4; ++n) acc[m][n] = (f4v){0.f, 0.f, 0.f, 0.f};
  const int arow = t0 + w * 32 + (l & 15);
  const int dcol = l & 15;
#pragma unroll
  for (int ks = 0; ks < 2; ++ks) {
    const int k0 = ks * 32 + (l >> 4) * 8;
    s8v af[2], bf[4];
#pragma unroll
    for (int m = 0; m < 2; ++m)
      af[m] = *(const s8v*)&timeqb[(size_t)(arow + m * 16) * DD + h * DHH + k0];
#pragma unroll
    for (int n = 0; n < 4; ++n)
      bf[n] = *(const s8v*)&Ms[(dcol + n * 16) * 72 + k0];
#pragma unroll
    for (int m = 0; m < 2; ++m)
#pragma unroll
      for (int n = 0; n < 4; ++n)
        acc[m][n] =
            __builtin_amdgcn_mfma_f32_16x16x32_bf16(af[m], bf[n], acc[m][n], 0, 0, 0);
  }
  const int trow = t0 + w * 32 + (l >> 4) * 4;
  float qs[2][4];
#pragma unroll
  for (int m = 0; m < 2; ++m)
#pragma unroll
    for (int r = 0; r < 4; ++r)
      qs[m][r] = qsum[(b * TT + trow + m * 16 + r) * HH + h];
#pragma unroll
  for (int m = 0; m < 2; ++m)
#pragma unroll
    for (int n = 0; n < 4; ++n)
#pragma unroll
      for (int r = 0; r < 4; ++r) {
        int i = b * TT + trow + m * 16 + r;
        loading[(size_t)i * DD + h * DHH + n * 16 + (l & 15)] =
            f2bf(qs[m][r] * acc[m][n][r]);
      }
}

// ---------------- LayerNorm ----------------
__global__ __launch_bounds__(256) void layernorm(
    const float* __restrict__ X, const float* __restrict__ gamma,
    const float* __restrict__ beta, float* __restrict__ out) {
  int i = blockIdx.x;
  const float* x = X + (size_t)i * 768;
  float vals[3];
  float s = 0.f, s2 = 0.f;
#pragma unroll
  for (int p = 0; p < 3; ++p) {
    float v = x[threadIdx.x + 256 * p];
    vals[p] = v;
    s += v;
    s2 += v * v;
  }
  s = wave_sum(s);
  s2 = wave_sum(s2);
  __shared__ float red[8];
  int w = threadIdx.x >> 6;
  if ((threadIdx.x & 63) == 0) {
    red[w] = s;
    red[4 + w] = s2;
  }
  __syncthreads();
  float stot = red[0] + red[1] + red[2] + red[3];
  float s2tot = red[4] + red[5] + red[6] + red[7];
  float mu = stot * (1.f / 768.f);
  float var = s2tot * (1.f / 768.f) - mu * mu;
  float rs = rsqrtf(var + 1e-5f);
#pragma unroll
  for (int p = 0; p < 3; ++p) {
    int j = threadIdx.x + 256 * p;
    out[(size_t)i * 768 + j] = (vals[p] - mu) * rs * gamma[j] + beta[j];
  }
}

extern "C" void kernel_launch(void* const* d_in, const int* in_sizes, int n_in,
                              void* d_out, int out_size, void* d_ws,
                              size_t ws_size, hipStream_t stream) {
  const float* states = (const float*)d_in[0];
  const int* amask    = (const int*)d_in[1];
  const float* Wq     = (const float*)d_in[2];
  const float* Wk     = (const float*)d_in[3];
  const float* bk     = (const float*)d_in[4];
  const float* Wv     = (const float*)d_in[5];
  const float* bv     = (const float*)d_in[6];
  const float* Wo     = (const float*)d_in[7];
  const float* bo     = (const float*)d_in[8];
  const float* qb     = (const float*)d_in[9];
  const float* tang   = (const float*)d_in[10];
  const float* hdelta = (const float*)d_in[11];
  const float* gamma  = (const float*)d_in[12];
  const float* beta   = (const float*)d_in[13];
  float* out = (float*)d_out;
  float* ws = (float*)d_ws;

  // compact workspace layout (58.8 MB total; float-unit offsets)
  u16* timeqb = (u16*)(ws);                 // bytes [0 .. 3,145,728)
  float* timek = ws + 786432;               // [3,145,728 .. 9,437,184)
  u16* qkvb   = (u16*)(ws + 2359296);       // [9,437,184 .. 28,311,552)
  u16* loadb  = (u16*)(ws + 2359296);       // [9,437,184 .. 15,728,640) reuse
  float* xbuf = ws + 3932160;               // [15,728,640 .. 28,311,552) reuse
  float* kvbuf = ws + 7077888;              // [28,311,552 .. 40,894,464)
  float* qsum = ws + 10223616;              // [40,894,464 .. 41,091,072)
  float* Mpart = ws + 10272768;             // [41,091,072 .. 47,382,528)
  float* Mt   = ws + 11845632;              // [47,382,528 .. 47,775,744)
  u16* Abf    = (u16*)(ws + 11943936);      // [47,775,744 .. 54,067,200)
  u16* Wqkvb  = (u16*)(ws + 13516800);      // [54,067,200 .. 57,606,144)
  u16* Wob    = (u16*)(ws + 14401536);      // [57,606,144 .. 58,785,792)

  time_tables<<<3072, 256, 0, stream>>>(tang, hdelta, timeqb, timek);
  convert_bf16<<<5376, 256, 0, stream>>>(states, Wq, Wk, Wv, Wo, Abf, Wqkvb, Wob);
  gemm_bt<0, 1><<<dim3(18, 32), 256, 0, stream>>>(Abf, Wqkvb, qkvb, nullptr,
                                                  nullptr, 4096, 2304, 768);
  fuse_qkv<<<12288, 256, 0, stream>>>(qkvb, bk, bv, qb, amask, kvbuf, qsum);
  calc_M<<<384, 256, 0, stream>>>(timek, kvbuf, Mpart);
  reduce_M<<<384, 256, 0, stream>>>(Mpart, Mt);
  calc_loading_mfma<<<dim3(16, 24), 256, 0, stream>>>(timeqb, Mt, qsum, loadb);
  gemm_bt<1, 0><<<dim3(6, 32), 256, 0, stream>>>(loadb, Wob, xbuf, bo, states,
                                                 4096, 768, 768);
  layernorm<<<4096, 256, 0, stream>>>(xbuf, gamma, beta, out);
}